// Round 17
// baseline (325.469 us; speedup 1.0000x reference)
//
#include <hip/hip_runtime.h>

// GCN: 2x GCNConv(+self-loop sym-norm) + ReLU, global mean pool, linear head.
// N=100000, E=1600000, G=100, D_IN=3, H=128, OUT=10.
//
// R16->R17: (1) agg2pool phase A 4-deep edge pipeline (VGPR was 32 after the
// MFMA conversion -> headroom to 64 at 8 waves/EU; phase A was L2-latency
// bound at VALUBusy 32%). MPB=16 group-per-node unchanged (R14's spill came
// from MPB=32's doubled live state, not unroll depth). (2) hist layout
// reverted to R15 (coalesced store in histconv; R16's transpose made the
// 196-block histogram store scattered cross-XCD -> tail +17us).
// Keep: MFMA 16x16x32 phase B, w2frag table, pooled zeroing in histconv.
//
// All kernels static + gcn364_ prefix (cross-.so symbol collisions caused the
// round-1 silent failure). Runtime dtype probe handles bf16/fp32 harness mode.

#define DIN 3
#define H 128
#define OUTF 10
#define NWEIGHT (384 + 128 + 16384 + 128 + 1280 + 10)  // W1,b1,W2,b2,Wl,bl
#define ECH 8192            // edges per slice
#define RGSH 9              // region = 512 nodes
#define RGSIZE 512
#define W2FRAG_N 16384      // 8 tiles * 4 kchunks * 64 lanes * 8 elems

typedef float gcn364_f2 __attribute__((ext_vector_type(2)));
typedef float gcn364_f4 __attribute__((ext_vector_type(4)));
typedef short gcn364_s8 __attribute__((ext_vector_type(8)));

__device__ __forceinline__ float gcn364_bf2f(unsigned short u) {
    return __uint_as_float(((unsigned int)u) << 16);
}
__device__ __forceinline__ unsigned short gcn364_f2bf(float f) {
    unsigned int u = __float_as_uint(f);
    u += 0x7FFFu + ((u >> 16) & 1u);   // round-to-nearest-even
    return (unsigned short)(u >> 16);
}

// per-wave dtype probe over x's first 256 ushorts: 1 -> fp32, 0 -> bf16.
__device__ __forceinline__ int gcn364_probe(const unsigned short* __restrict__ xs16) {
    int lane = threadIdx.x & 63;
    int outl = 0;
    #pragma unroll
    for (int k = 0; k < 4; k++) {
        unsigned short u = xs16[lane * 4 + k];
        int e = (u >> 7) & 0xFF;
        outl += (e < 100 || e > 140) ? 1 : 0;
    }
    #pragma unroll
    for (int d = 1; d < 64; d <<= 1) outl += __shfl_xor(outl, d);
    return (outl > 32) ? 1 : 0;
}

// histconv: blocks < S build the per-slice region histogram (coalesced
// hist[s*RG + r] store); all blocks also convert x -> xf4 / weights -> wf,
// build the W2 B-fragment table (bf16), zero pooled, publish flag.
static __global__ void gcn364_histconv(const void* __restrict__ x,
                                       const void* __restrict__ W1, const void* __restrict__ b1,
                                       const void* __restrict__ W2, const void* __restrict__ b2,
                                       const void* __restrict__ Wl, const void* __restrict__ bl,
                                       int* __restrict__ flag,
                                       float4* __restrict__ xf4, float* __restrict__ wf,
                                       unsigned short* __restrict__ w2frag,
                                       float* __restrict__ pooled,
                                       const int* __restrict__ edst,
                                       int* __restrict__ hist,
                                       int N, int E, int S, int RG, int GH) {
    __shared__ int h[256];
    if (blockIdx.x < (unsigned)S) {
        h[threadIdx.x] = 0;
        __syncthreads();
        int elo = blockIdx.x * ECH;
        int ehi = elo + ECH; if (ehi > E) ehi = E;
        for (int e = elo + threadIdx.x; e < ehi; e += 256)
            atomicAdd(&h[edst[e] >> RGSH], 1);
        __syncthreads();
        if (threadIdx.x < RG) hist[blockIdx.x * RG + threadIdx.x] = h[threadIdx.x];
    }
    int i = blockIdx.x * blockDim.x + threadIdx.x;
    if (i < GH) pooled[i] = 0.0f;
    int total = N + NWEIGHT;
    if ((int)blockIdx.x * 256 < total) {
        int fl = gcn364_probe((const unsigned short*)x);
        if (i == 0) *flag = fl;
        if (i < N) {
            float a, b, c;
            if (fl) {
                const float* xs = (const float*)x;
                a = xs[3 * i]; b = xs[3 * i + 1]; c = xs[3 * i + 2];
            } else {
                const unsigned short* xs = (const unsigned short*)x;
                a = gcn364_bf2f(xs[3 * i]);
                b = gcn364_bf2f(xs[3 * i + 1]);
                c = gcn364_bf2f(xs[3 * i + 2]);
            }
            xf4[i] = make_float4(a, b, c, 0.f);
        } else if (i < total) {
            int j = i - N;
            const void* srcp;
            if      (j < 384)                       { srcp = W1; }
            else if ((j -= 384)   < 128)            { srcp = b1; }
            else if ((j -= 128)   < 16384)          { srcp = W2; }
            else if ((j -= 16384) < 128)            { srcp = b2; }
            else if ((j -= 128)   < 1280)           { srcp = Wl; }
            else    { j -= 1280;                      srcp = bl; }
            wf[i - N] = fl ? ((const float*)srcp)[j]
                           : gcn364_bf2f(((const unsigned short*)srcp)[j]);
        }
        // W2 B-fragment table: frag[t][c][lane][j] = bf16(W2[k][n]),
        // k = c*32 + (lane>>4)*8 + j, n = t*16 + (lane&15)
        if (i < W2FRAG_N) {
            int fl2 = fl;
            int j = i & 7;
            int l = (i >> 3) & 63;
            int c = (i >> 9) & 3;
            int t = i >> 11;
            int k = c * 32 + (l >> 4) * 8 + j;
            int n = t * 16 + (l & 15);
            float w = fl2 ? ((const float*)W2)[k * H + n]
                          : gcn364_bf2f(((const unsigned short*)W2)[k * H + n]);
            w2frag[i] = gcn364_f2bf(w);
        }
    }
}

// scanH (1 block): hist[s][r] -> per-(slice,region) local prefix;
// regionBase[r] = exclusive scan of region totals; regionBase[RG] = E.
static __global__ void gcn364_scanH(int* __restrict__ hist,
                                    int* __restrict__ regionBase,
                                    int S, int RG, int E) {
    int r = threadIdx.x;
    int tot = 0;
    if (r < RG) {
        for (int s = 0; s < S; s++) {
            int idx = s * RG + r;
            int c = hist[idx];
            hist[idx] = tot;       // local prefix within region r
            tot += c;
        }
    }
    __shared__ int sh[256];
    sh[threadIdx.x] = (r < RG) ? tot : 0;
    __syncthreads();
    for (int d = 1; d < 256; d <<= 1) {
        int val = (threadIdx.x >= d) ? sh[threadIdx.x - d] : 0;
        __syncthreads();
        sh[threadIdx.x] += val;
        __syncthreads();
    }
    if (r < RG) regionBase[r] = sh[r] - tot;   // exclusive
    if (threadIdx.x == 0) regionBase[RG] = E;
}

// partition: slice s scatters its edges into region-major epack order using
// LDS cursors seeded from hist+regionBase. Plain stores only.
// epack = (dlocal << 17) | src
static __global__ void gcn364_partition(const int* __restrict__ src,
                                        const int* __restrict__ dst,
                                        const int* __restrict__ hist,
                                        const int* __restrict__ regionBase,
                                        int* __restrict__ epack,
                                        int E, int RG) {
    __shared__ int cur[256];
    int s = blockIdx.x;
    if (threadIdx.x < RG)
        cur[threadIdx.x] = hist[s * RG + threadIdx.x] + regionBase[threadIdx.x];
    __syncthreads();
    int elo = s * ECH;
    int ehi = elo + ECH; if (ehi > E) ehi = E;
    for (int e = elo + threadIdx.x; e < ehi; e += 256) {
        int d = dst[e];
        int sv = src[e];
        int p = atomicAdd(&cur[d >> RGSH], 1);
        epack[p] = ((d & (RGSIZE - 1)) << 17) | sv;
    }
}

// build: one block per region. LDS deg hist over the region's contiguous
// epack run -> LDS scan -> absolute off[] (inclusive ends) -> LDS-cursor
// esrc placement. Also dinvs + xf4 scaling for the region's nodes.
static __global__ void gcn364_build(const int* __restrict__ epack,
                                    const int* __restrict__ regionBase,
                                    int* __restrict__ off,
                                    int* __restrict__ esrc,
                                    float4* __restrict__ xf4,
                                    int N) {
    __shared__ int sdeg[RGSIZE];
    __shared__ int stmp[256];
    int r = blockIdx.x;
    int nlo = r << RGSH;
    int nn = N - nlo; if (nn > RGSIZE) nn = RGSIZE;
    int e0 = regionBase[r];
    int e1 = regionBase[r + 1];
    int t = threadIdx.x;

    sdeg[t] = 0; sdeg[t + 256] = 0;
    __syncthreads();
    for (int p = e0 + t; p < e1; p += 256)
        atomicAdd(&sdeg[epack[p] >> 17], 1);
    __syncthreads();

    int a0 = sdeg[2 * t];
    int a1 = sdeg[2 * t + 1];
    int psum = a0 + a1;
    stmp[t] = psum;
    __syncthreads();
    for (int d = 1; d < 256; d <<= 1) {
        int val = (t >= d) ? stmp[t - d] : 0;
        __syncthreads();
        stmp[t] += val;
        __syncthreads();
    }
    int excl = stmp[t] - psum;

    if (2 * t < nn)     off[nlo + 2 * t]     = e0 + excl + a0;
    if (2 * t + 1 < nn) off[nlo + 2 * t + 1] = e0 + excl + a0 + a1;
    if (2 * t < nn) {
        float di = rsqrtf((float)a0 + 1.0f);
        float4 xv = xf4[nlo + 2 * t];
        xv.x *= di; xv.y *= di; xv.z *= di; xv.w = di;
        xf4[nlo + 2 * t] = xv;
    }
    if (2 * t + 1 < nn) {
        float di = rsqrtf((float)a1 + 1.0f);
        float4 xv = xf4[nlo + 2 * t + 1];
        xv.x *= di; xv.y *= di; xv.z *= di; xv.w = di;
        xf4[nlo + 2 * t + 1] = xv;
    }
    sdeg[2 * t]     = e0 + excl;
    sdeg[2 * t + 1] = e0 + excl + a0;
    __syncthreads();
    for (int p = e0 + t; p < e1; p += 256) {
        int v = epack[p];
        int q = atomicAdd(&sdeg[v >> 17], 1);
        esrc[q] = v & 0x1FFFF;
    }
}

// Layer-1 aggregation -> u4 records. 16 lanes per node, 4 nodes per wave.
static __global__ void gcn364_aggu(const int* __restrict__ esrc,
                                   const int* __restrict__ off,
                                   const float4* __restrict__ xf4,
                                   float4* __restrict__ u4, int N) {
    int lane = threadIdx.x & 63;
    int wv = threadIdx.x >> 6;
    int grp = lane >> 4;
    int sub = lane & 15;
    int i = (blockIdx.x * 4 + wv) * 4 + grp;

    float a0 = 0.f, a1 = 0.f, a2 = 0.f;
    if (i < N) {
        int p0 = (i == 0) ? 0 : off[i - 1];
        int p1 = off[i];
        for (int p = p0 + sub; p < p1; p += 16) {
            float4 sv = xf4[esrc[p]];
            a0 += sv.x; a1 += sv.y; a2 += sv.z;
        }
    }
    for (int d = 1; d < 16; d <<= 1) {
        a0 += __shfl_xor(a0, d);
        a1 += __shfl_xor(a1, d);
        a2 += __shfl_xor(a2, d);
    }
    if (i < N && sub == 0) {
        float4 xi = xf4[i];
        float di = xi.w;
        u4[i] = make_float4(di * (a0 + xi.x), di * (a1 + xi.y), di * (a2 + xi.z), di);
    }
}

// per-edge layer-1 row recompute + accumulate (packed dual-fp32)
__device__ __forceinline__ void gcn364_edge(const float4 u,
                                            const gcn364_f2* wa2, const gcn364_f2* wb2,
                                            const gcn364_f2* wc2, const gcn364_f2* bb2,
                                            gcn364_f2* acc) {
    gcn364_f2 ux = {u.x, u.x}, uy = {u.y, u.y}, uz = {u.z, u.z}, uw = {u.w, u.w};
    gcn364_f2 zero = {0.f, 0.f};
    #pragma unroll
    for (int q = 0; q < 4; q++) {
        gcn364_f2 t = ux * wa2[q] + uy * wb2[q] + uz * wc2[q] + bb2[q];
        t = __builtin_elementwise_max(t, zero);
        acc[q] += uw * t;
    }
}

// Fused layer-2: phase A = per-edge layer-1 recompute + aggregation,
// 4-deep pipelined u4 gathers; V tile -> bf16 LDS in MFMA A-frag layout.
// Phase B = MFMA 16x16x32 bf16 GEMM over W2 fragments + relu + mean-pool.
#define MPB 16
static __global__ __launch_bounds__(256, 8) void gcn364_agg2pool(
        const int* __restrict__ esrc, const int* __restrict__ off,
        const float4* __restrict__ u4,
        const float* __restrict__ w1f, const float* __restrict__ b1f,
        const unsigned short* __restrict__ w2frag, const float* __restrict__ b2f,
        const int* __restrict__ batch, float* __restrict__ pooled, int N) {
    __shared__ unsigned short vshb[MPB][H + 8];   // bf16 V tile, A-frag friendly
    int i0 = blockIdx.x * MPB;
    int tid = threadIdx.x;
    int wave = tid >> 6;
    int lane = tid & 63;
    int grp = lane >> 4;
    int sub = lane & 15;
    int node = wave * 4 + grp;
    int i = i0 + node;

    gcn364_f2 wa2[4], wb2[4], wc2[4], bb2[4];
    #pragma unroll
    for (int q = 0; q < 4; q++) {
        int f = sub * 8 + q * 2;
        wa2[q] = (gcn364_f2){w1f[f], w1f[f + 1]};
        wb2[q] = (gcn364_f2){w1f[H + f], w1f[H + f + 1]};
        wc2[q] = (gcn364_f2){w1f[2 * H + f], w1f[2 * H + f + 1]};
        bb2[q] = (gcn364_f2){b1f[f], b1f[f + 1]};
    }

    gcn364_f2 acc[4];
    acc[0] = acc[1] = acc[2] = acc[3] = (gcn364_f2){0.f, 0.f};
    float di = 0.f;
    if (i < N) {
        int p0 = (i == 0) ? 0 : off[i - 1];
        int p1 = off[i];
        int p = p0;
        for (; p + 4 <= p1; p += 4) {
            int s0 = esrc[p], s1 = esrc[p + 1], s2 = esrc[p + 2], s3 = esrc[p + 3];
            float4 uA = u4[s0];
            float4 uB = u4[s1];
            float4 uC = u4[s2];
            float4 uD = u4[s3];
            gcn364_edge(uA, wa2, wb2, wc2, bb2, acc);
            gcn364_edge(uB, wa2, wb2, wc2, bb2, acc);
            gcn364_edge(uC, wa2, wb2, wc2, bb2, acc);
            gcn364_edge(uD, wa2, wb2, wc2, bb2, acc);
        }
        for (; p < p1; p++) {
            float4 uA = u4[esrc[p]];
            gcn364_edge(uA, wa2, wb2, wc2, bb2, acc);
        }
        float4 uS = u4[i];   // self-loop
        gcn364_edge(uS, wa2, wb2, wc2, bb2, acc);
        di = uS.w;
    }
    {   // V row -> bf16 LDS (feats sub*8..sub*8+7)
        gcn364_s8 o;
        o[0] = (short)gcn364_f2bf(acc[0].x * di);
        o[1] = (short)gcn364_f2bf(acc[0].y * di);
        o[2] = (short)gcn364_f2bf(acc[1].x * di);
        o[3] = (short)gcn364_f2bf(acc[1].y * di);
        o[4] = (short)gcn364_f2bf(acc[2].x * di);
        o[5] = (short)gcn364_f2bf(acc[2].y * di);
        o[6] = (short)gcn364_f2bf(acc[3].x * di);
        o[7] = (short)gcn364_f2bf(acc[3].y * di);
        *(gcn364_s8*)&vshb[node][sub * 8] = o;
    }
    __syncthreads();

    // Phase B: MFMA. A[m][k]: m = lane&15 (node), k = quad*8+j over chunks.
    int m = lane & 15;
    int quad = lane >> 4;
    gcn364_s8 af[4];
    #pragma unroll
    for (int c = 0; c < 4; c++)
        af[c] = *(const gcn364_s8*)&vshb[m][c * 32 + quad * 8];

    #pragma unroll
    for (int tt = 0; tt < 2; tt++) {
        int t = wave * 2 + tt;                // n-tile 0..7
        gcn364_f4 cacc = {0.f, 0.f, 0.f, 0.f};
        #pragma unroll
        for (int c = 0; c < 4; c++) {
            gcn364_s8 bf8 = *(const gcn364_s8*)&w2frag[(((t * 4 + c) * 64) + lane) * 8];
            cacc = __builtin_amdgcn_mfma_f32_16x16x32_bf16(af[c], bf8, cacc, 0, 0, 0);
        }
        // C/D: col = lane&15 (feat within tile), row = (lane>>4)*4 + reg (node)
        int feat = t * 16 + (lane & 15);
        float bb = b2f[feat];
        int baseRow = (lane >> 4) * 4;
        float sum = 0.0f;
        int curg = -1;
        #pragma unroll
        for (int r = 0; r < 4; r++) {
            int ii = i0 + baseRow + r;
            if (ii >= N) continue;
            float val = fmaxf(cacc[r] + bb, 0.0f);
            int g = batch[ii];
            if (g != curg) {
                if (curg >= 0) atomicAdd(&pooled[curg * H + feat], sum);
                curg = g;
                sum = 0.0f;
            }
            sum += val;
        }
        if (curg >= 0) atomicAdd(&pooled[curg * H + feat], sum);
    }
}

// out[g] = (pooled[g]/cnt_g) @ Wl + bl  -> detected dtype.
static __global__ void gcn364_final(const float* __restrict__ pooled,
                                    const int* __restrict__ batch,
                                    const float* __restrict__ wlf,
                                    const float* __restrict__ blf,
                                    const int* __restrict__ flag,
                                    void* __restrict__ out, int N, int G) {
    int g = blockIdx.x;
    int o = threadIdx.x;
    if (g >= G || o >= OUTF) return;
    int lo = 0, hi = N;
    while (lo < hi) { int m = (lo + hi) >> 1; if (batch[m] < g) lo = m + 1; else hi = m; }
    int a = lo;
    lo = 0; hi = N;
    while (lo < hi) { int m = (lo + hi) >> 1; if (batch[m] < g + 1) lo = m + 1; else hi = m; }
    float cn = (float)(lo - a);
    float inv = 1.0f / fmaxf(cn, 1.0f);
    float acc = 0.0f;
    for (int k = 0; k < H; k++)
        acc += pooled[g * H + k] * wlf[k * OUTF + o];
    float v = acc * inv + blf[o];
    if (*flag) ((float*)out)[g * OUTF + o] = v;
    else       ((unsigned short*)out)[g * OUTF + o] = gcn364_f2bf(v);
}

extern "C" void kernel_launch(void* const* d_in, const int* in_sizes, int n_in,
                              void* d_out, int out_size, void* d_ws, size_t ws_size,
                              hipStream_t stream) {
    const void* x  = d_in[0];
    const int* edge_index = (const int*)d_in[1];
    const int* batch      = (const int*)d_in[2];
    const void* W1 = d_in[3];
    const void* b1 = d_in[4];
    const void* W2 = d_in[5];
    const void* b2 = d_in[6];
    const void* Wl = d_in[7];
    const void* bl = d_in[8];

    const int N = in_sizes[0] / DIN;
    const int E = in_sizes[1] / 2;
    const int G = out_size / OUTF;
    const int* src = edge_index;
    const int* dst = edge_index + E;
    const int S  = (E + ECH - 1) / ECH;       // edge slices
    const int RG = (N + RGSIZE - 1) >> RGSH;  // node regions (<= 256)
    const int GH = G * H;

    // ---- workspace layout (no memset needed; histconv zeroes pooled) ----
    char* wsb = (char*)d_ws;
    float* pooled     = (float*)wsb;                              // G*H
    int*   hist       = (int*)(pooled + (size_t)GH);              // S*RG
    int*   regionBase = hist + (size_t)S * RG;                    // RG+1
    int*   off        = regionBase + RG + 1;                      // N
    int*   flag       = off + N;                                  // 1
    size_t ofs = (((size_t)((char*)(flag + 1) - wsb)) + 15) & ~(size_t)15;
    float4* xf4  = (float4*)(wsb + ofs);                          // N float4
    float4* u4   = xf4 + N;                                       // N float4
    float*  wf   = (float*)(u4 + N);                              // NWEIGHT
    size_t ofs2 = (((size_t)((char*)(wf + NWEIGHT) - wsb)) + 15) & ~(size_t)15;
    unsigned short* w2frag = (unsigned short*)(wsb + ofs2);       // 16384 ushort
    int*    epack = (int*)(w2frag + W2FRAG_N);                    // E
    int*    esrc  = epack + E;                                    // E

    float* w1f = wf;
    float* b1f = w1f + 384;
    float* b2f = b1f + 128 + 16384;
    float* wlf = b2f + 128;
    float* blf = wlf + 1280;

    {
        int convBlocks = (N + NWEIGHT + 255) / 256;
        int gmax = (S > convBlocks) ? S : convBlocks;
        gcn364_histconv<<<gmax, 256, 0, stream>>>(
            x, W1, b1, W2, b2, Wl, bl, flag, xf4, wf, w2frag, pooled,
            dst, hist, N, E, S, RG, GH);
    }
    gcn364_scanH<<<1, 256, 0, stream>>>(hist, regionBase, S, RG, E);
    gcn364_partition<<<S, 256, 0, stream>>>(src, dst, hist, regionBase, epack, E, RG);
    gcn364_build<<<RG, 256, 0, stream>>>(epack, regionBase, off, esrc, xf4, N);
    gcn364_aggu<<<(N + 15) / 16, 256, 0, stream>>>(esrc, off, xf4, u4, N);
    gcn364_agg2pool<<<(N + MPB - 1) / MPB, 256, 0, stream>>>(
        esrc, off, u4, w1f, b1f, w2frag, b2f, batch, pooled, N);
    gcn364_final<<<G, 64, 0, stream>>>(pooled, batch, wlf, blf, flag, d_out, N, G);
}

// Round 18
// 295.333 us; speedup vs baseline: 1.1020x; 1.1020x over previous
//
#include <hip/hip_runtime.h>

// GCN: 2x GCNConv(+self-loop sym-norm) + ReLU, global mean pool, linear head.
// N=100000, E=1600000, G=100, D_IN=3, H=128, OUT=10.
//
// R17->R18: pure recombination of validated configs. R16 proved the MFMA
// phase B (agg2pool 122->111us) but regressed the tail with a hist
// transpose; R17 fixed the tail but its 4-deep phase A spilled (WRITE
// 22->110MB at pinned VGPR=32 — compiler refuses >2 in-flight u4 gathers;
// same signature as R14). This round: R15 build pipeline (coalesced
// hist[s*RG+r] store) + R16 agg2pool EXACTLY (2-deep phase A, MFMA phase B).
//
// All kernels static + gcn364_ prefix (cross-.so symbol collisions caused the
// round-1 silent failure). Runtime dtype probe handles bf16/fp32 harness mode.

#define DIN 3
#define H 128
#define OUTF 10
#define NWEIGHT (384 + 128 + 16384 + 128 + 1280 + 10)  // W1,b1,W2,b2,Wl,bl
#define ECH 8192            // edges per slice
#define RGSH 9              // region = 512 nodes
#define RGSIZE 512
#define W2FRAG_N 16384      // 8 tiles * 4 kchunks * 64 lanes * 8 elems

typedef float gcn364_f2 __attribute__((ext_vector_type(2)));
typedef float gcn364_f4 __attribute__((ext_vector_type(4)));
typedef short gcn364_s8 __attribute__((ext_vector_type(8)));

__device__ __forceinline__ float gcn364_bf2f(unsigned short u) {
    return __uint_as_float(((unsigned int)u) << 16);
}
__device__ __forceinline__ unsigned short gcn364_f2bf(float f) {
    unsigned int u = __float_as_uint(f);
    u += 0x7FFFu + ((u >> 16) & 1u);   // round-to-nearest-even
    return (unsigned short)(u >> 16);
}

// per-wave dtype probe over x's first 256 ushorts: 1 -> fp32, 0 -> bf16.
__device__ __forceinline__ int gcn364_probe(const unsigned short* __restrict__ xs16) {
    int lane = threadIdx.x & 63;
    int outl = 0;
    #pragma unroll
    for (int k = 0; k < 4; k++) {
        unsigned short u = xs16[lane * 4 + k];
        int e = (u >> 7) & 0xFF;
        outl += (e < 100 || e > 140) ? 1 : 0;
    }
    #pragma unroll
    for (int d = 1; d < 64; d <<= 1) outl += __shfl_xor(outl, d);
    return (outl > 32) ? 1 : 0;
}

// histconv: blocks < S build the per-slice region histogram (coalesced
// hist[s*RG + r] store); all blocks also convert x -> xf4 / weights -> wf,
// build the W2 B-fragment table (bf16), zero pooled, publish flag.
static __global__ void gcn364_histconv(const void* __restrict__ x,
                                       const void* __restrict__ W1, const void* __restrict__ b1,
                                       const void* __restrict__ W2, const void* __restrict__ b2,
                                       const void* __restrict__ Wl, const void* __restrict__ bl,
                                       int* __restrict__ flag,
                                       float4* __restrict__ xf4, float* __restrict__ wf,
                                       unsigned short* __restrict__ w2frag,
                                       float* __restrict__ pooled,
                                       const int* __restrict__ edst,
                                       int* __restrict__ hist,
                                       int N, int E, int S, int RG, int GH) {
    __shared__ int h[256];
    if (blockIdx.x < (unsigned)S) {
        h[threadIdx.x] = 0;
        __syncthreads();
        int elo = blockIdx.x * ECH;
        int ehi = elo + ECH; if (ehi > E) ehi = E;
        for (int e = elo + threadIdx.x; e < ehi; e += 256)
            atomicAdd(&h[edst[e] >> RGSH], 1);
        __syncthreads();
        if (threadIdx.x < RG) hist[blockIdx.x * RG + threadIdx.x] = h[threadIdx.x];
    }
    int i = blockIdx.x * blockDim.x + threadIdx.x;
    if (i < GH) pooled[i] = 0.0f;
    int total = N + NWEIGHT;
    if ((int)blockIdx.x * 256 < total) {
        int fl = gcn364_probe((const unsigned short*)x);
        if (i == 0) *flag = fl;
        if (i < N) {
            float a, b, c;
            if (fl) {
                const float* xs = (const float*)x;
                a = xs[3 * i]; b = xs[3 * i + 1]; c = xs[3 * i + 2];
            } else {
                const unsigned short* xs = (const unsigned short*)x;
                a = gcn364_bf2f(xs[3 * i]);
                b = gcn364_bf2f(xs[3 * i + 1]);
                c = gcn364_bf2f(xs[3 * i + 2]);
            }
            xf4[i] = make_float4(a, b, c, 0.f);
        } else if (i < total) {
            int j = i - N;
            const void* srcp;
            if      (j < 384)                       { srcp = W1; }
            else if ((j -= 384)   < 128)            { srcp = b1; }
            else if ((j -= 128)   < 16384)          { srcp = W2; }
            else if ((j -= 16384) < 128)            { srcp = b2; }
            else if ((j -= 128)   < 1280)           { srcp = Wl; }
            else    { j -= 1280;                      srcp = bl; }
            wf[i - N] = fl ? ((const float*)srcp)[j]
                           : gcn364_bf2f(((const unsigned short*)srcp)[j]);
        }
        // W2 B-fragment table: frag[t][c][lane][j] = bf16(W2[k][n]),
        // k = c*32 + (lane>>4)*8 + j, n = t*16 + (lane&15)
        if (i < W2FRAG_N) {
            int fl2 = fl;
            int j = i & 7;
            int l = (i >> 3) & 63;
            int c = (i >> 9) & 3;
            int t = i >> 11;
            int k = c * 32 + (l >> 4) * 8 + j;
            int n = t * 16 + (l & 15);
            float w = fl2 ? ((const float*)W2)[k * H + n]
                          : gcn364_bf2f(((const unsigned short*)W2)[k * H + n]);
            w2frag[i] = gcn364_f2bf(w);
        }
    }
}

// scanH (1 block): hist[s][r] -> per-(slice,region) local prefix;
// regionBase[r] = exclusive scan of region totals; regionBase[RG] = E.
static __global__ void gcn364_scanH(int* __restrict__ hist,
                                    int* __restrict__ regionBase,
                                    int S, int RG, int E) {
    int r = threadIdx.x;
    int tot = 0;
    if (r < RG) {
        for (int s = 0; s < S; s++) {
            int idx = s * RG + r;
            int c = hist[idx];
            hist[idx] = tot;       // local prefix within region r
            tot += c;
        }
    }
    __shared__ int sh[256];
    sh[threadIdx.x] = (r < RG) ? tot : 0;
    __syncthreads();
    for (int d = 1; d < 256; d <<= 1) {
        int val = (threadIdx.x >= d) ? sh[threadIdx.x - d] : 0;
        __syncthreads();
        sh[threadIdx.x] += val;
        __syncthreads();
    }
    if (r < RG) regionBase[r] = sh[r] - tot;   // exclusive
    if (threadIdx.x == 0) regionBase[RG] = E;
}

// partition: slice s scatters its edges into region-major epack order using
// LDS cursors seeded from hist+regionBase. Plain stores only.
// epack = (dlocal << 17) | src
static __global__ void gcn364_partition(const int* __restrict__ src,
                                        const int* __restrict__ dst,
                                        const int* __restrict__ hist,
                                        const int* __restrict__ regionBase,
                                        int* __restrict__ epack,
                                        int E, int RG) {
    __shared__ int cur[256];
    int s = blockIdx.x;
    if (threadIdx.x < RG)
        cur[threadIdx.x] = hist[s * RG + threadIdx.x] + regionBase[threadIdx.x];
    __syncthreads();
    int elo = s * ECH;
    int ehi = elo + ECH; if (ehi > E) ehi = E;
    for (int e = elo + threadIdx.x; e < ehi; e += 256) {
        int d = dst[e];
        int sv = src[e];
        int p = atomicAdd(&cur[d >> RGSH], 1);
        epack[p] = ((d & (RGSIZE - 1)) << 17) | sv;
    }
}

// build: one block per region. LDS deg hist over the region's contiguous
// epack run -> LDS scan -> absolute off[] (inclusive ends) -> LDS-cursor
// esrc placement. Also dinvs + xf4 scaling for the region's nodes.
static __global__ void gcn364_build(const int* __restrict__ epack,
                                    const int* __restrict__ regionBase,
                                    int* __restrict__ off,
                                    int* __restrict__ esrc,
                                    float4* __restrict__ xf4,
                                    int N) {
    __shared__ int sdeg[RGSIZE];
    __shared__ int stmp[256];
    int r = blockIdx.x;
    int nlo = r << RGSH;
    int nn = N - nlo; if (nn > RGSIZE) nn = RGSIZE;
    int e0 = regionBase[r];
    int e1 = regionBase[r + 1];
    int t = threadIdx.x;

    sdeg[t] = 0; sdeg[t + 256] = 0;
    __syncthreads();
    for (int p = e0 + t; p < e1; p += 256)
        atomicAdd(&sdeg[epack[p] >> 17], 1);
    __syncthreads();

    int a0 = sdeg[2 * t];
    int a1 = sdeg[2 * t + 1];
    int psum = a0 + a1;
    stmp[t] = psum;
    __syncthreads();
    for (int d = 1; d < 256; d <<= 1) {
        int val = (t >= d) ? stmp[t - d] : 0;
        __syncthreads();
        stmp[t] += val;
        __syncthreads();
    }
    int excl = stmp[t] - psum;

    if (2 * t < nn)     off[nlo + 2 * t]     = e0 + excl + a0;
    if (2 * t + 1 < nn) off[nlo + 2 * t + 1] = e0 + excl + a0 + a1;
    if (2 * t < nn) {
        float di = rsqrtf((float)a0 + 1.0f);
        float4 xv = xf4[nlo + 2 * t];
        xv.x *= di; xv.y *= di; xv.z *= di; xv.w = di;
        xf4[nlo + 2 * t] = xv;
    }
    if (2 * t + 1 < nn) {
        float di = rsqrtf((float)a1 + 1.0f);
        float4 xv = xf4[nlo + 2 * t + 1];
        xv.x *= di; xv.y *= di; xv.z *= di; xv.w = di;
        xf4[nlo + 2 * t + 1] = xv;
    }
    sdeg[2 * t]     = e0 + excl;
    sdeg[2 * t + 1] = e0 + excl + a0;
    __syncthreads();
    for (int p = e0 + t; p < e1; p += 256) {
        int v = epack[p];
        int q = atomicAdd(&sdeg[v >> 17], 1);
        esrc[q] = v & 0x1FFFF;
    }
}

// Layer-1 aggregation -> u4 records. 16 lanes per node, 4 nodes per wave.
static __global__ void gcn364_aggu(const int* __restrict__ esrc,
                                   const int* __restrict__ off,
                                   const float4* __restrict__ xf4,
                                   float4* __restrict__ u4, int N) {
    int lane = threadIdx.x & 63;
    int wv = threadIdx.x >> 6;
    int grp = lane >> 4;
    int sub = lane & 15;
    int i = (blockIdx.x * 4 + wv) * 4 + grp;

    float a0 = 0.f, a1 = 0.f, a2 = 0.f;
    if (i < N) {
        int p0 = (i == 0) ? 0 : off[i - 1];
        int p1 = off[i];
        for (int p = p0 + sub; p < p1; p += 16) {
            float4 sv = xf4[esrc[p]];
            a0 += sv.x; a1 += sv.y; a2 += sv.z;
        }
    }
    for (int d = 1; d < 16; d <<= 1) {
        a0 += __shfl_xor(a0, d);
        a1 += __shfl_xor(a1, d);
        a2 += __shfl_xor(a2, d);
    }
    if (i < N && sub == 0) {
        float4 xi = xf4[i];
        float di = xi.w;
        u4[i] = make_float4(di * (a0 + xi.x), di * (a1 + xi.y), di * (a2 + xi.z), di);
    }
}

// per-edge layer-1 row recompute + accumulate (packed dual-fp32)
__device__ __forceinline__ void gcn364_edge(const float4 u,
                                            const gcn364_f2* wa2, const gcn364_f2* wb2,
                                            const gcn364_f2* wc2, const gcn364_f2* bb2,
                                            gcn364_f2* acc) {
    gcn364_f2 ux = {u.x, u.x}, uy = {u.y, u.y}, uz = {u.z, u.z}, uw = {u.w, u.w};
    gcn364_f2 zero = {0.f, 0.f};
    #pragma unroll
    for (int q = 0; q < 4; q++) {
        gcn364_f2 t = ux * wa2[q] + uy * wb2[q] + uz * wc2[q] + bb2[q];
        t = __builtin_elementwise_max(t, zero);
        acc[q] += uw * t;
    }
}

// Fused layer-2 (R16-exact): phase A = per-edge layer-1 recompute +
// aggregation (2-deep), V tile -> bf16 LDS in MFMA A-frag layout.
// Phase B = MFMA 16x16x32 bf16 GEMM over W2 fragments + relu + mean-pool.
#define MPB 16
static __global__ __launch_bounds__(256, 8) void gcn364_agg2pool(
        const int* __restrict__ esrc, const int* __restrict__ off,
        const float4* __restrict__ u4,
        const float* __restrict__ w1f, const float* __restrict__ b1f,
        const unsigned short* __restrict__ w2frag, const float* __restrict__ b2f,
        const int* __restrict__ batch, float* __restrict__ pooled, int N) {
    __shared__ unsigned short vshb[MPB][H + 8];   // bf16 V tile, A-frag friendly
    int i0 = blockIdx.x * MPB;
    int tid = threadIdx.x;
    int wave = tid >> 6;
    int lane = tid & 63;
    int grp = lane >> 4;
    int sub = lane & 15;
    int node = wave * 4 + grp;
    int i = i0 + node;

    gcn364_f2 wa2[4], wb2[4], wc2[4], bb2[4];
    #pragma unroll
    for (int q = 0; q < 4; q++) {
        int f = sub * 8 + q * 2;
        wa2[q] = (gcn364_f2){w1f[f], w1f[f + 1]};
        wb2[q] = (gcn364_f2){w1f[H + f], w1f[H + f + 1]};
        wc2[q] = (gcn364_f2){w1f[2 * H + f], w1f[2 * H + f + 1]};
        bb2[q] = (gcn364_f2){b1f[f], b1f[f + 1]};
    }

    gcn364_f2 acc[4];
    acc[0] = acc[1] = acc[2] = acc[3] = (gcn364_f2){0.f, 0.f};
    float di = 0.f;
    if (i < N) {
        int p0 = (i == 0) ? 0 : off[i - 1];
        int p1 = off[i];
        int p = p0;
        for (; p + 2 <= p1; p += 2) {
            float4 uA = u4[esrc[p]];
            float4 uB = u4[esrc[p + 1]];
            gcn364_edge(uA, wa2, wb2, wc2, bb2, acc);
            gcn364_edge(uB, wa2, wb2, wc2, bb2, acc);
        }
        if (p < p1) {
            float4 uA = u4[esrc[p]];
            gcn364_edge(uA, wa2, wb2, wc2, bb2, acc);
        }
        float4 uS = u4[i];   // self-loop
        gcn364_edge(uS, wa2, wb2, wc2, bb2, acc);
        di = uS.w;
    }
    {   // V row -> bf16 LDS (feats sub*8..sub*8+7)
        gcn364_s8 o;
        o[0] = (short)gcn364_f2bf(acc[0].x * di);
        o[1] = (short)gcn364_f2bf(acc[0].y * di);
        o[2] = (short)gcn364_f2bf(acc[1].x * di);
        o[3] = (short)gcn364_f2bf(acc[1].y * di);
        o[4] = (short)gcn364_f2bf(acc[2].x * di);
        o[5] = (short)gcn364_f2bf(acc[2].y * di);
        o[6] = (short)gcn364_f2bf(acc[3].x * di);
        o[7] = (short)gcn364_f2bf(acc[3].y * di);
        *(gcn364_s8*)&vshb[node][sub * 8] = o;
    }
    __syncthreads();

    // Phase B: MFMA. A[m][k]: m = lane&15 (node), k = quad*8+j over chunks.
    int m = lane & 15;
    int quad = lane >> 4;
    gcn364_s8 af[4];
    #pragma unroll
    for (int c = 0; c < 4; c++)
        af[c] = *(const gcn364_s8*)&vshb[m][c * 32 + quad * 8];

    #pragma unroll
    for (int tt = 0; tt < 2; tt++) {
        int t = wave * 2 + tt;                // n-tile 0..7
        gcn364_f4 cacc = {0.f, 0.f, 0.f, 0.f};
        #pragma unroll
        for (int c = 0; c < 4; c++) {
            gcn364_s8 bf8 = *(const gcn364_s8*)&w2frag[(((t * 4 + c) * 64) + lane) * 8];
            cacc = __builtin_amdgcn_mfma_f32_16x16x32_bf16(af[c], bf8, cacc, 0, 0, 0);
        }
        // C/D: col = lane&15 (feat within tile), row = (lane>>4)*4 + reg (node)
        int feat = t * 16 + (lane & 15);
        float bb = b2f[feat];
        int baseRow = (lane >> 4) * 4;
        float sum = 0.0f;
        int curg = -1;
        #pragma unroll
        for (int r = 0; r < 4; r++) {
            int ii = i0 + baseRow + r;
            if (ii >= N) continue;
            float val = fmaxf(cacc[r] + bb, 0.0f);
            int g = batch[ii];
            if (g != curg) {
                if (curg >= 0) atomicAdd(&pooled[curg * H + feat], sum);
                curg = g;
                sum = 0.0f;
            }
            sum += val;
        }
        if (curg >= 0) atomicAdd(&pooled[curg * H + feat], sum);
    }
}

// out[g] = (pooled[g]/cnt_g) @ Wl + bl  -> detected dtype.
static __global__ void gcn364_final(const float* __restrict__ pooled,
                                    const int* __restrict__ batch,
                                    const float* __restrict__ wlf,
                                    const float* __restrict__ blf,
                                    const int* __restrict__ flag,
                                    void* __restrict__ out, int N, int G) {
    int g = blockIdx.x;
    int o = threadIdx.x;
    if (g >= G || o >= OUTF) return;
    int lo = 0, hi = N;
    while (lo < hi) { int m = (lo + hi) >> 1; if (batch[m] < g) lo = m + 1; else hi = m; }
    int a = lo;
    lo = 0; hi = N;
    while (lo < hi) { int m = (lo + hi) >> 1; if (batch[m] < g + 1) lo = m + 1; else hi = m; }
    float cn = (float)(lo - a);
    float inv = 1.0f / fmaxf(cn, 1.0f);
    float acc = 0.0f;
    for (int k = 0; k < H; k++)
        acc += pooled[g * H + k] * wlf[k * OUTF + o];
    float v = acc * inv + blf[o];
    if (*flag) ((float*)out)[g * OUTF + o] = v;
    else       ((unsigned short*)out)[g * OUTF + o] = gcn364_f2bf(v);
}

extern "C" void kernel_launch(void* const* d_in, const int* in_sizes, int n_in,
                              void* d_out, int out_size, void* d_ws, size_t ws_size,
                              hipStream_t stream) {
    const void* x  = d_in[0];
    const int* edge_index = (const int*)d_in[1];
    const int* batch      = (const int*)d_in[2];
    const void* W1 = d_in[3];
    const void* b1 = d_in[4];
    const void* W2 = d_in[5];
    const void* b2 = d_in[6];
    const void* Wl = d_in[7];
    const void* bl = d_in[8];

    const int N = in_sizes[0] / DIN;
    const int E = in_sizes[1] / 2;
    const int G = out_size / OUTF;
    const int* src = edge_index;
    const int* dst = edge_index + E;
    const int S  = (E + ECH - 1) / ECH;       // edge slices
    const int RG = (N + RGSIZE - 1) >> RGSH;  // node regions (<= 256)
    const int GH = G * H;

    // ---- workspace layout (no memset needed; histconv zeroes pooled) ----
    char* wsb = (char*)d_ws;
    float* pooled     = (float*)wsb;                              // G*H
    int*   hist       = (int*)(pooled + (size_t)GH);              // S*RG
    int*   regionBase = hist + (size_t)S * RG;                    // RG+1
    int*   off        = regionBase + RG + 1;                      // N
    int*   flag       = off + N;                                  // 1
    size_t ofs = (((size_t)((char*)(flag + 1) - wsb)) + 15) & ~(size_t)15;
    float4* xf4  = (float4*)(wsb + ofs);                          // N float4
    float4* u4   = xf4 + N;                                       // N float4
    float*  wf   = (float*)(u4 + N);                              // NWEIGHT
    size_t ofs2 = (((size_t)((char*)(wf + NWEIGHT) - wsb)) + 15) & ~(size_t)15;
    unsigned short* w2frag = (unsigned short*)(wsb + ofs2);       // 16384 ushort
    int*    epack = (int*)(w2frag + W2FRAG_N);                    // E
    int*    esrc  = epack + E;                                    // E

    float* w1f = wf;
    float* b1f = w1f + 384;
    float* b2f = b1f + 128 + 16384;
    float* wlf = b2f + 128;
    float* blf = wlf + 1280;

    {
        int convBlocks = (N + NWEIGHT + 255) / 256;
        int gmax = (S > convBlocks) ? S : convBlocks;
        gcn364_histconv<<<gmax, 256, 0, stream>>>(
            x, W1, b1, W2, b2, Wl, bl, flag, xf4, wf, w2frag, pooled,
            dst, hist, N, E, S, RG, GH);
    }
    gcn364_scanH<<<1, 256, 0, stream>>>(hist, regionBase, S, RG, E);
    gcn364_partition<<<S, 256, 0, stream>>>(src, dst, hist, regionBase, epack, E, RG);
    gcn364_build<<<RG, 256, 0, stream>>>(epack, regionBase, off, esrc, xf4, N);
    gcn364_aggu<<<(N + 15) / 16, 256, 0, stream>>>(esrc, off, xf4, u4, N);
    gcn364_agg2pool<<<(N + MPB - 1) / MPB, 256, 0, stream>>>(
        esrc, off, u4, w1f, b1f, w2frag, b2f, batch, pooled, N);
    gcn364_final<<<G, 64, 0, stream>>>(pooled, batch, wlf, blf, flag, d_out, N, G);
}

// Round 19
// 276.697 us; speedup vs baseline: 1.1763x; 1.0674x over previous
//
#include <hip/hip_runtime.h>

// GCN: 2x GCNConv(+self-loop sym-norm) + ReLU, global mean pool, linear head.
// N=100000, E=1600000, G=100, D_IN=3, H=128, OUT=10.
//
// R18->R19: agg2pool phase A restructured to LANE-PARALLEL gather with LDS
// staging: per 16-edge chunk, lane sub loads esrc[base+sub] (coalesced) and
// gathers u4 (16 loads in flight per group, 8x MLP vs the 2-deep broadcast
// walk), stages to LDS; group then consumes the staged records via
// same-address LDS broadcast reads (free; in-order within a wave -> no
// barrier). Register pressure unchanged (1 in-flight float4/lane), which
// sidesteps the R14/R17 spill trap (compiler refuses >2 in-flight gathers
// per lane). Phase A was 70% dependent-load stalls (VALU floor ~35us of
// 121us at VALUBusy 29%). Everything else R18-exact.
//
// All kernels static + gcn364_ prefix (cross-.so symbol collisions caused the
// round-1 silent failure). Runtime dtype probe handles bf16/fp32 harness mode.

#define DIN 3
#define H 128
#define OUTF 10
#define NWEIGHT (384 + 128 + 16384 + 128 + 1280 + 10)  // W1,b1,W2,b2,Wl,bl
#define ECH 8192            // edges per slice
#define RGSH 9              // region = 512 nodes
#define RGSIZE 512
#define W2FRAG_N 16384      // 8 tiles * 4 kchunks * 64 lanes * 8 elems

typedef float gcn364_f2 __attribute__((ext_vector_type(2)));
typedef float gcn364_f4 __attribute__((ext_vector_type(4)));
typedef short gcn364_s8 __attribute__((ext_vector_type(8)));

__device__ __forceinline__ float gcn364_bf2f(unsigned short u) {
    return __uint_as_float(((unsigned int)u) << 16);
}
__device__ __forceinline__ unsigned short gcn364_f2bf(float f) {
    unsigned int u = __float_as_uint(f);
    u += 0x7FFFu + ((u >> 16) & 1u);   // round-to-nearest-even
    return (unsigned short)(u >> 16);
}

// per-wave dtype probe over x's first 256 ushorts: 1 -> fp32, 0 -> bf16.
__device__ __forceinline__ int gcn364_probe(const unsigned short* __restrict__ xs16) {
    int lane = threadIdx.x & 63;
    int outl = 0;
    #pragma unroll
    for (int k = 0; k < 4; k++) {
        unsigned short u = xs16[lane * 4 + k];
        int e = (u >> 7) & 0xFF;
        outl += (e < 100 || e > 140) ? 1 : 0;
    }
    #pragma unroll
    for (int d = 1; d < 64; d <<= 1) outl += __shfl_xor(outl, d);
    return (outl > 32) ? 1 : 0;
}

// histconv: blocks < S build the per-slice region histogram (coalesced
// hist[s*RG + r] store); all blocks also convert x -> xf4 / weights -> wf,
// build the W2 B-fragment table (bf16), zero pooled, publish flag.
static __global__ void gcn364_histconv(const void* __restrict__ x,
                                       const void* __restrict__ W1, const void* __restrict__ b1,
                                       const void* __restrict__ W2, const void* __restrict__ b2,
                                       const void* __restrict__ Wl, const void* __restrict__ bl,
                                       int* __restrict__ flag,
                                       float4* __restrict__ xf4, float* __restrict__ wf,
                                       unsigned short* __restrict__ w2frag,
                                       float* __restrict__ pooled,
                                       const int* __restrict__ edst,
                                       int* __restrict__ hist,
                                       int N, int E, int S, int RG, int GH) {
    __shared__ int h[256];
    if (blockIdx.x < (unsigned)S) {
        h[threadIdx.x] = 0;
        __syncthreads();
        int elo = blockIdx.x * ECH;
        int ehi = elo + ECH; if (ehi > E) ehi = E;
        for (int e = elo + threadIdx.x; e < ehi; e += 256)
            atomicAdd(&h[edst[e] >> RGSH], 1);
        __syncthreads();
        if (threadIdx.x < RG) hist[blockIdx.x * RG + threadIdx.x] = h[threadIdx.x];
    }
    int i = blockIdx.x * blockDim.x + threadIdx.x;
    if (i < GH) pooled[i] = 0.0f;
    int total = N + NWEIGHT;
    if ((int)blockIdx.x * 256 < total) {
        int fl = gcn364_probe((const unsigned short*)x);
        if (i == 0) *flag = fl;
        if (i < N) {
            float a, b, c;
            if (fl) {
                const float* xs = (const float*)x;
                a = xs[3 * i]; b = xs[3 * i + 1]; c = xs[3 * i + 2];
            } else {
                const unsigned short* xs = (const unsigned short*)x;
                a = gcn364_bf2f(xs[3 * i]);
                b = gcn364_bf2f(xs[3 * i + 1]);
                c = gcn364_bf2f(xs[3 * i + 2]);
            }
            xf4[i] = make_float4(a, b, c, 0.f);
        } else if (i < total) {
            int j = i - N;
            const void* srcp;
            if      (j < 384)                       { srcp = W1; }
            else if ((j -= 384)   < 128)            { srcp = b1; }
            else if ((j -= 128)   < 16384)          { srcp = W2; }
            else if ((j -= 16384) < 128)            { srcp = b2; }
            else if ((j -= 128)   < 1280)           { srcp = Wl; }
            else    { j -= 1280;                      srcp = bl; }
            wf[i - N] = fl ? ((const float*)srcp)[j]
                           : gcn364_bf2f(((const unsigned short*)srcp)[j]);
        }
        // W2 B-fragment table: frag[t][c][lane][j] = bf16(W2[k][n]),
        // k = c*32 + (lane>>4)*8 + j, n = t*16 + (lane&15)
        if (i < W2FRAG_N) {
            int fl2 = fl;
            int j = i & 7;
            int l = (i >> 3) & 63;
            int c = (i >> 9) & 3;
            int t = i >> 11;
            int k = c * 32 + (l >> 4) * 8 + j;
            int n = t * 16 + (l & 15);
            float w = fl2 ? ((const float*)W2)[k * H + n]
                          : gcn364_bf2f(((const unsigned short*)W2)[k * H + n]);
            w2frag[i] = gcn364_f2bf(w);
        }
    }
}

// scanH (1 block): hist[s][r] -> per-(slice,region) local prefix;
// regionBase[r] = exclusive scan of region totals; regionBase[RG] = E.
static __global__ void gcn364_scanH(int* __restrict__ hist,
                                    int* __restrict__ regionBase,
                                    int S, int RG, int E) {
    int r = threadIdx.x;
    int tot = 0;
    if (r < RG) {
        for (int s = 0; s < S; s++) {
            int idx = s * RG + r;
            int c = hist[idx];
            hist[idx] = tot;       // local prefix within region r
            tot += c;
        }
    }
    __shared__ int sh[256];
    sh[threadIdx.x] = (r < RG) ? tot : 0;
    __syncthreads();
    for (int d = 1; d < 256; d <<= 1) {
        int val = (threadIdx.x >= d) ? sh[threadIdx.x - d] : 0;
        __syncthreads();
        sh[threadIdx.x] += val;
        __syncthreads();
    }
    if (r < RG) regionBase[r] = sh[r] - tot;   // exclusive
    if (threadIdx.x == 0) regionBase[RG] = E;
}

// partition: slice s scatters its edges into region-major epack order using
// LDS cursors seeded from hist+regionBase. Plain stores only.
// epack = (dlocal << 17) | src
static __global__ void gcn364_partition(const int* __restrict__ src,
                                        const int* __restrict__ dst,
                                        const int* __restrict__ hist,
                                        const int* __restrict__ regionBase,
                                        int* __restrict__ epack,
                                        int E, int RG) {
    __shared__ int cur[256];
    int s = blockIdx.x;
    if (threadIdx.x < RG)
        cur[threadIdx.x] = hist[s * RG + threadIdx.x] + regionBase[threadIdx.x];
    __syncthreads();
    int elo = s * ECH;
    int ehi = elo + ECH; if (ehi > E) ehi = E;
    for (int e = elo + threadIdx.x; e < ehi; e += 256) {
        int d = dst[e];
        int sv = src[e];
        int p = atomicAdd(&cur[d >> RGSH], 1);
        epack[p] = ((d & (RGSIZE - 1)) << 17) | sv;
    }
}

// build: one block per region. LDS deg hist over the region's contiguous
// epack run -> LDS scan -> absolute off[] (inclusive ends) -> LDS-cursor
// esrc placement. Also dinvs + xf4 scaling for the region's nodes.
static __global__ void gcn364_build(const int* __restrict__ epack,
                                    const int* __restrict__ regionBase,
                                    int* __restrict__ off,
                                    int* __restrict__ esrc,
                                    float4* __restrict__ xf4,
                                    int N) {
    __shared__ int sdeg[RGSIZE];
    __shared__ int stmp[256];
    int r = blockIdx.x;
    int nlo = r << RGSH;
    int nn = N - nlo; if (nn > RGSIZE) nn = RGSIZE;
    int e0 = regionBase[r];
    int e1 = regionBase[r + 1];
    int t = threadIdx.x;

    sdeg[t] = 0; sdeg[t + 256] = 0;
    __syncthreads();
    for (int p = e0 + t; p < e1; p += 256)
        atomicAdd(&sdeg[epack[p] >> 17], 1);
    __syncthreads();

    int a0 = sdeg[2 * t];
    int a1 = sdeg[2 * t + 1];
    int psum = a0 + a1;
    stmp[t] = psum;
    __syncthreads();
    for (int d = 1; d < 256; d <<= 1) {
        int val = (t >= d) ? stmp[t - d] : 0;
        __syncthreads();
        stmp[t] += val;
        __syncthreads();
    }
    int excl = stmp[t] - psum;

    if (2 * t < nn)     off[nlo + 2 * t]     = e0 + excl + a0;
    if (2 * t + 1 < nn) off[nlo + 2 * t + 1] = e0 + excl + a0 + a1;
    if (2 * t < nn) {
        float di = rsqrtf((float)a0 + 1.0f);
        float4 xv = xf4[nlo + 2 * t];
        xv.x *= di; xv.y *= di; xv.z *= di; xv.w = di;
        xf4[nlo + 2 * t] = xv;
    }
    if (2 * t + 1 < nn) {
        float di = rsqrtf((float)a1 + 1.0f);
        float4 xv = xf4[nlo + 2 * t + 1];
        xv.x *= di; xv.y *= di; xv.z *= di; xv.w = di;
        xf4[nlo + 2 * t + 1] = xv;
    }
    sdeg[2 * t]     = e0 + excl;
    sdeg[2 * t + 1] = e0 + excl + a0;
    __syncthreads();
    for (int p = e0 + t; p < e1; p += 256) {
        int v = epack[p];
        int q = atomicAdd(&sdeg[v >> 17], 1);
        esrc[q] = v & 0x1FFFF;
    }
}

// Layer-1 aggregation -> u4 records. 16 lanes per node, 4 nodes per wave.
static __global__ void gcn364_aggu(const int* __restrict__ esrc,
                                   const int* __restrict__ off,
                                   const float4* __restrict__ xf4,
                                   float4* __restrict__ u4, int N) {
    int lane = threadIdx.x & 63;
    int wv = threadIdx.x >> 6;
    int grp = lane >> 4;
    int sub = lane & 15;
    int i = (blockIdx.x * 4 + wv) * 4 + grp;

    float a0 = 0.f, a1 = 0.f, a2 = 0.f;
    if (i < N) {
        int p0 = (i == 0) ? 0 : off[i - 1];
        int p1 = off[i];
        for (int p = p0 + sub; p < p1; p += 16) {
            float4 sv = xf4[esrc[p]];
            a0 += sv.x; a1 += sv.y; a2 += sv.z;
        }
    }
    for (int d = 1; d < 16; d <<= 1) {
        a0 += __shfl_xor(a0, d);
        a1 += __shfl_xor(a1, d);
        a2 += __shfl_xor(a2, d);
    }
    if (i < N && sub == 0) {
        float4 xi = xf4[i];
        float di = xi.w;
        u4[i] = make_float4(di * (a0 + xi.x), di * (a1 + xi.y), di * (a2 + xi.z), di);
    }
}

// per-edge layer-1 row recompute + accumulate (packed dual-fp32)
__device__ __forceinline__ void gcn364_edge(const float4 u,
                                            const gcn364_f2* wa2, const gcn364_f2* wb2,
                                            const gcn364_f2* wc2, const gcn364_f2* bb2,
                                            gcn364_f2* acc) {
    gcn364_f2 ux = {u.x, u.x}, uy = {u.y, u.y}, uz = {u.z, u.z}, uw = {u.w, u.w};
    gcn364_f2 zero = {0.f, 0.f};
    #pragma unroll
    for (int q = 0; q < 4; q++) {
        gcn364_f2 t = ux * wa2[q] + uy * wb2[q] + uz * wc2[q] + bb2[q];
        t = __builtin_elementwise_max(t, zero);
        acc[q] += uw * t;
    }
}

// Fused layer-2: phase A = lane-parallel 16-edge-chunk gather (LDS staged,
// broadcast consume) + per-edge layer-1 recompute; V tile -> bf16 LDS in
// MFMA A-frag layout. Phase B = MFMA 16x16x32 bf16 GEMM + relu + mean-pool.
#define MPB 16
static __global__ __launch_bounds__(256, 8) void gcn364_agg2pool(
        const int* __restrict__ esrc, const int* __restrict__ off,
        const float4* __restrict__ u4,
        const float* __restrict__ w1f, const float* __restrict__ b1f,
        const unsigned short* __restrict__ w2frag, const float* __restrict__ b2f,
        const int* __restrict__ batch, float* __restrict__ pooled, int N) {
    __shared__ unsigned short vshb[MPB][H + 8];   // bf16 V tile, A-frag friendly
    __shared__ float4 stage[16][16];              // per-group staged u4 records
    int i0 = blockIdx.x * MPB;
    int tid = threadIdx.x;
    int wave = tid >> 6;
    int lane = tid & 63;
    int grp = lane >> 4;
    int sub = lane & 15;
    int node = wave * 4 + grp;
    int i = i0 + node;

    gcn364_f2 wa2[4], wb2[4], wc2[4], bb2[4];
    #pragma unroll
    for (int q = 0; q < 4; q++) {
        int f = sub * 8 + q * 2;
        wa2[q] = (gcn364_f2){w1f[f], w1f[f + 1]};
        wb2[q] = (gcn364_f2){w1f[H + f], w1f[H + f + 1]};
        wc2[q] = (gcn364_f2){w1f[2 * H + f], w1f[2 * H + f + 1]};
        bb2[q] = (gcn364_f2){b1f[f], b1f[f + 1]};
    }

    gcn364_f2 acc[4];
    acc[0] = acc[1] = acc[2] = acc[3] = (gcn364_f2){0.f, 0.f};
    float di = 0.f;
    if (i < N) {
        int p0 = (i == 0) ? 0 : off[i - 1];
        int p1 = off[i];
        for (int base = p0; base < p1; base += 16) {
            int cnt = p1 - base; if (cnt > 16) cnt = 16;
            // lane-parallel gather: coalesced esrc read + 16 independent
            // u4 loads in flight per group
            float4 uv = make_float4(0.f, 0.f, 0.f, 0.f);
            if (sub < cnt) uv = u4[esrc[base + sub]];
            stage[node][sub] = uv;   // DS ops in-order within wave: no barrier
            for (int j = 0; j < cnt; j++) {
                float4 u = stage[node][j];   // same-address broadcast read
                gcn364_edge(u, wa2, wb2, wc2, bb2, acc);
            }
        }
        float4 uS = u4[i];   // self-loop
        gcn364_edge(uS, wa2, wb2, wc2, bb2, acc);
        di = uS.w;
    }
    {   // V row -> bf16 LDS (feats sub*8..sub*8+7)
        gcn364_s8 o;
        o[0] = (short)gcn364_f2bf(acc[0].x * di);
        o[1] = (short)gcn364_f2bf(acc[0].y * di);
        o[2] = (short)gcn364_f2bf(acc[1].x * di);
        o[3] = (short)gcn364_f2bf(acc[1].y * di);
        o[4] = (short)gcn364_f2bf(acc[2].x * di);
        o[5] = (short)gcn364_f2bf(acc[2].y * di);
        o[6] = (short)gcn364_f2bf(acc[3].x * di);
        o[7] = (short)gcn364_f2bf(acc[3].y * di);
        *(gcn364_s8*)&vshb[node][sub * 8] = o;
    }
    __syncthreads();

    // Phase B: MFMA. A[m][k]: m = lane&15 (node), k = quad*8+j over chunks.
    int m = lane & 15;
    int quad = lane >> 4;
    gcn364_s8 af[4];
    #pragma unroll
    for (int c = 0; c < 4; c++)
        af[c] = *(const gcn364_s8*)&vshb[m][c * 32 + quad * 8];

    #pragma unroll
    for (int tt = 0; tt < 2; tt++) {
        int t = wave * 2 + tt;                // n-tile 0..7
        gcn364_f4 cacc = {0.f, 0.f, 0.f, 0.f};
        #pragma unroll
        for (int c = 0; c < 4; c++) {
            gcn364_s8 bf8 = *(const gcn364_s8*)&w2frag[(((t * 4 + c) * 64) + lane) * 8];
            cacc = __builtin_amdgcn_mfma_f32_16x16x32_bf16(af[c], bf8, cacc, 0, 0, 0);
        }
        // C/D: col = lane&15 (feat within tile), row = (lane>>4)*4 + reg (node)
        int feat = t * 16 + (lane & 15);
        float bb = b2f[feat];
        int baseRow = (lane >> 4) * 4;
        float sum = 0.0f;
        int curg = -1;
        #pragma unroll
        for (int r = 0; r < 4; r++) {
            int ii = i0 + baseRow + r;
            if (ii >= N) continue;
            float val = fmaxf(cacc[r] + bb, 0.0f);
            int g = batch[ii];
            if (g != curg) {
                if (curg >= 0) atomicAdd(&pooled[curg * H + feat], sum);
                curg = g;
                sum = 0.0f;
            }
            sum += val;
        }
        if (curg >= 0) atomicAdd(&pooled[curg * H + feat], sum);
    }
}

// out[g] = (pooled[g]/cnt_g) @ Wl + bl  -> detected dtype.
static __global__ void gcn364_final(const float* __restrict__ pooled,
                                    const int* __restrict__ batch,
                                    const float* __restrict__ wlf,
                                    const float* __restrict__ blf,
                                    const int* __restrict__ flag,
                                    void* __restrict__ out, int N, int G) {
    int g = blockIdx.x;
    int o = threadIdx.x;
    if (g >= G || o >= OUTF) return;
    int lo = 0, hi = N;
    while (lo < hi) { int m = (lo + hi) >> 1; if (batch[m] < g) lo = m + 1; else hi = m; }
    int a = lo;
    lo = 0; hi = N;
    while (lo < hi) { int m = (lo + hi) >> 1; if (batch[m] < g + 1) lo = m + 1; else hi = m; }
    float cn = (float)(lo - a);
    float inv = 1.0f / fmaxf(cn, 1.0f);
    float acc = 0.0f;
    for (int k = 0; k < H; k++)
        acc += pooled[g * H + k] * wlf[k * OUTF + o];
    float v = acc * inv + blf[o];
    if (*flag) ((float*)out)[g * OUTF + o] = v;
    else       ((unsigned short*)out)[g * OUTF + o] = gcn364_f2bf(v);
}

extern "C" void kernel_launch(void* const* d_in, const int* in_sizes, int n_in,
                              void* d_out, int out_size, void* d_ws, size_t ws_size,
                              hipStream_t stream) {
    const void* x  = d_in[0];
    const int* edge_index = (const int*)d_in[1];
    const int* batch      = (const int*)d_in[2];
    const void* W1 = d_in[3];
    const void* b1 = d_in[4];
    const void* W2 = d_in[5];
    const void* b2 = d_in[6];
    const void* Wl = d_in[7];
    const void* bl = d_in[8];

    const int N = in_sizes[0] / DIN;
    const int E = in_sizes[1] / 2;
    const int G = out_size / OUTF;
    const int* src = edge_index;
    const int* dst = edge_index + E;
    const int S  = (E + ECH - 1) / ECH;       // edge slices
    const int RG = (N + RGSIZE - 1) >> RGSH;  // node regions (<= 256)
    const int GH = G * H;

    // ---- workspace layout (no memset needed; histconv zeroes pooled) ----
    char* wsb = (char*)d_ws;
    float* pooled     = (float*)wsb;                              // G*H
    int*   hist       = (int*)(pooled + (size_t)GH);              // S*RG
    int*   regionBase = hist + (size_t)S * RG;                    // RG+1
    int*   off        = regionBase + RG + 1;                      // N
    int*   flag       = off + N;                                  // 1
    size_t ofs = (((size_t)((char*)(flag + 1) - wsb)) + 15) & ~(size_t)15;
    float4* xf4  = (float4*)(wsb + ofs);                          // N float4
    float4* u4   = xf4 + N;                                       // N float4
    float*  wf   = (float*)(u4 + N);                              // NWEIGHT
    size_t ofs2 = (((size_t)((char*)(wf + NWEIGHT) - wsb)) + 15) & ~(size_t)15;
    unsigned short* w2frag = (unsigned short*)(wsb + ofs2);       // 16384 ushort
    int*    epack = (int*)(w2frag + W2FRAG_N);                    // E
    int*    esrc  = epack + E;                                    // E

    float* w1f = wf;
    float* b1f = w1f + 384;
    float* b2f = b1f + 128 + 16384;
    float* wlf = b2f + 128;
    float* blf = wlf + 1280;

    {
        int convBlocks = (N + NWEIGHT + 255) / 256;
        int gmax = (S > convBlocks) ? S : convBlocks;
        gcn364_histconv<<<gmax, 256, 0, stream>>>(
            x, W1, b1, W2, b2, Wl, bl, flag, xf4, wf, w2frag, pooled,
            dst, hist, N, E, S, RG, GH);
    }
    gcn364_scanH<<<1, 256, 0, stream>>>(hist, regionBase, S, RG, E);
    gcn364_partition<<<S, 256, 0, stream>>>(src, dst, hist, regionBase, epack, E, RG);
    gcn364_build<<<RG, 256, 0, stream>>>(epack, regionBase, off, esrc, xf4, N);
    gcn364_aggu<<<(N + 15) / 16, 256, 0, stream>>>(esrc, off, xf4, u4, N);
    gcn364_agg2pool<<<(N + MPB - 1) / MPB, 256, 0, stream>>>(
        esrc, off, u4, w1f, b1f, w2frag, b2f, batch, pooled, N);
    gcn364_final<<<G, 64, 0, stream>>>(pooled, batch, wlf, blf, flag, d_out, N, G);
}